// Round 16
// baseline (113.917 us; speedup 1.0000x reference)
//
#include <hip/hip_runtime.h>
#include <hip/hip_fp16.h>
#include <math.h>

#define NAG 6
#define CC  64
#define HH  128
#define WW  128
#define HWT 16384
#define HWP 8192             // packed f16 pairs per (agent,channel) plane
#define BN_EPS 1e-5f
#define WFRAG_PJ_OFF (24 * 64 * 8)   // halves: P/Q/W slots first, then proj slots

typedef unsigned int u32;
typedef __fp16 f16x2v __attribute__((ext_vector_type(2)));
typedef __fp16 f16x8  __attribute__((ext_vector_type(8)));
typedef float  f32x4  __attribute__((ext_vector_type(4)));

// packed-f16 tanh-form gelu, exp2-folded
__device__ __forceinline__ u32 gelu_pk(u32 xu) {
    __half2 x = __builtin_bit_cast(__half2, xu);
    __half2 s = __hmul2(x, x);
    __half2 m = __hfma2(s, __float2half2_rn(-0.10294535f),
                        __float2half2_rn(-2.30226045f));
    __half2 e = h2exp2(__hmul2(x, m));
    __half2 r = h2rcp(__hadd2(e, __float2half2_rn(1.0f)));
    return __builtin_bit_cast(u32, __hmul2(x, r));
}

// ---------------- setup: min/max slots + weight prepack (one launch) ----------------
__global__ __launch_bounds__(256) void k_setup(
    const float* __restrict__ a1w, const float* __restrict__ vw,
    const float* __restrict__ pjw, __fp16* __restrict__ wfrag,
    u32* __restrict__ mm)
{
    int t = blockIdx.x * 256 + threadIdx.x;
    if (t < NAG) mm[t] = 0x7F800000u;        // +inf (min slots)
    else if (t < 2 * NAG) mm[t] = 0u;        // 0 (max; conf >= 0)
    if (t >= 32 * 64) return;
    int lane = t & 63;
    int slot = t >> 6;
    bool pj = slot >= 24;
    int s = pj ? slot - 24 : slot;
    int ot = s >> 1, kf = s & 1;
    int o  = (pj ? ot : (ot & 3)) * 16 + (lane & 15);
    int ch = kf * 32 + (lane >> 4) * 8;
    const float* src;
    if (pj)          src = pjw + o * CC + ch;
    else if (ot < 4) src = a1w + o * 2 * CC + ch;            // A1 (P)
    else if (ot < 8) src = a1w + o * 2 * CC + CC + ch;       // A2 (Q)
    else             src = vw  + o * CC + ch;                // V  (W)
    __fp16* dst = wfrag + ((size_t)slot * 64 + lane) * 8;
    #pragma unroll
    for (int j = 0; j < 8; ++j) dst[j] = (__fp16)src[j];
}

// ---------------- confidence maps (pre-normalization) + per-agent min/max ----------------
// vectorized: 4 px per thread via float4 (16 B/lane)
__global__ __launch_bounds__(256) void k_conf(
    const float* __restrict__ raw,
    const float* __restrict__ w1, const float* __restrict__ b1,
    const float* __restrict__ gamma, const float* __restrict__ beta,
    const float* __restrict__ mean, const float* __restrict__ var,
    const float* __restrict__ w2, const float* __restrict__ b2,
    float* __restrict__ conf, u32* __restrict__ mm)
{
    const int n = blockIdx.y;
    const int p = (blockIdx.x * 256 + threadIdx.x) * 4;
    const float* x = raw + (size_t)(n * CC) * HWT + p;

    f32x4 a[4];
    #pragma unroll
    for (int o = 0; o < 4; ++o) a[o] = (f32x4){0.f, 0.f, 0.f, 0.f};

    #pragma unroll 8
    for (int c = 0; c < CC; ++c) {
        f32x4 v = *(const f32x4*)(x + (size_t)c * HWT);
        #pragma unroll
        for (int o = 0; o < 4; ++o)
            a[o] += w1[o * CC + c] * v;
    }
    f32x4 h2 = (f32x4){b2[0], b2[0], b2[0], b2[0]};
    #pragma unroll
    for (int o = 0; o < 4; ++o) {
        float sc = gamma[o] * rsqrtf(var[o] + BN_EPS);
        float off = (b1[o] - mean[o]) * sc + beta[o];
        f32x4 hb = a[o] * sc + off;
        #pragma unroll
        for (int q = 0; q < 4; ++q) hb[q] = fmaxf(hb[q], 0.f);
        h2 += w2[o] * hb;
    }
    #pragma unroll
    for (int q = 0; q < 4; ++q) h2[q] = fmaxf(h2[q], 0.f);
    *(f32x4*)(conf + n * HWT + p) = h2;

    float mn = fminf(fminf(h2[0], h2[1]), fminf(h2[2], h2[3]));
    float mx = fmaxf(fmaxf(h2[0], h2[1]), fmaxf(h2[2], h2[3]));
    #pragma unroll
    for (int off = 32; off > 0; off >>= 1) {
        mn = fminf(mn, __shfl_xor(mn, off, 64));
        mx = fmaxf(mx, __shfl_xor(mx, off, 64));
    }
    __shared__ float smn[4], smx[4];
    int wid = threadIdx.x >> 6, lane = threadIdx.x & 63;
    if (lane == 0) { smn[wid] = mn; smx[wid] = mx; }
    __syncthreads();
    if (threadIdx.x == 0) {
        mn = fminf(fminf(smn[0], smn[1]), fminf(smn[2], smn[3]));
        mx = fmaxf(fmaxf(smx[0], smx[1]), fmaxf(smx[2], smx[3]));
        atomicMin(&mm[n], __float_as_uint(mn));
        atomicMax(&mm[n + NAG], __float_as_uint(mx));
    }
}

// ---------------- MFMA GEMM: P/Q (f16) + W (f16, conf-scaled) in one pass over raw ----------------
__global__ __launch_bounds__(256) void k_pqv(
    const float* __restrict__ raw, const __fp16* __restrict__ wfrag,
    const float* __restrict__ vb, const float* __restrict__ conf,
    const u32* __restrict__ mm,
    u32* __restrict__ Ph, u32* __restrict__ Qh, u32* __restrict__ Wh)
{
    const int n   = blockIdx.y;
    const int px0 = blockIdx.x * 128;
    const int t = threadIdx.x, lane = t & 63, wv = t >> 6;
    const int lm = lane & 15, kg = lane >> 4;
    const int pxw = px0 + wv * 32;
    const int pxl = pxw + lm;           // A-frag px (+ mt*16)
    const int pxs = pxw + kg * 4;       // store px base (+ mt*16)

    const float* rawn = raw + (size_t)n * CC * HWT;

    f16x8 afr[2][2];
    #pragma unroll
    for (int mt = 0; mt < 2; ++mt) {
        #pragma unroll
        for (int kf = 0; kf < 2; ++kf) {
            const float* base = rawn + (size_t)(kf * 32 + kg * 8) * HWT + pxl + mt * 16;
            f16x8 a;
            #pragma unroll
            for (int p = 0; p < 4; ++p) {
                f16x2v h = __builtin_amdgcn_cvt_pkrtz(base[(2 * p) * HWT],
                                                      base[(2 * p + 1) * HWT]);
                a[2 * p] = h.x; a[2 * p + 1] = h.y;
            }
            afr[mt][kf] = a;
        }
    }

    const float mn = __uint_as_float(mm[n]);
    const float mx = __uint_as_float(mm[n + NAG]);
    const float inv = 1.f / (mx - mn);
    f32x4 cn[2];
    #pragma unroll
    for (int mt = 0; mt < 2; ++mt) {
        f32x4 cv = *(const f32x4*)(conf + n * HWT + pxs + mt * 16);
        cn[mt] = (cv - mn) * inv;
    }

    #pragma unroll
    for (int ot = 0; ot < 12; ++ot) {
        f16x8 b0 = *(const f16x8*)(wfrag + ((size_t)(ot * 2 + 0) * 64 + lane) * 8);
        f16x8 b1 = *(const f16x8*)(wfrag + ((size_t)(ot * 2 + 1) * 64 + lane) * 8);
        const int o = (ot & 3) * 16 + lm;
        #pragma unroll
        for (int mt = 0; mt < 2; ++mt) {
            f32x4 acc = (f32x4){0.f, 0.f, 0.f, 0.f};
            acc = __builtin_amdgcn_mfma_f32_16x16x32_f16(afr[mt][0], b0, acc, 0, 0, 0);
            acc = __builtin_amdgcn_mfma_f32_16x16x32_f16(afr[mt][1], b1, acc, 0, 0, 0);
            const int pxb = pxs + mt * 16;
            f32x4 r;
            u32* plane;
            if (ot < 8) {
                r = acc;
                plane = (ot < 4 ? Ph : Qh) + (size_t)(n * CC + o) * HWP + (pxb >> 1);
            } else {
                r = (acc + vb[o]) * cn[mt];
                plane = Wh + (size_t)(n * CC + o) * HWP + (pxb >> 1);
            }
            f16x2v h0 = __builtin_amdgcn_cvt_pkrtz(r[0], r[1]);
            f16x2v h1 = __builtin_amdgcn_cvt_pkrtz(r[2], r[3]);
            *(uint2*)plane = make_uint2(__builtin_bit_cast(u32, h0),
                                        __builtin_bit_cast(u32, h1));
        }
    }
}

// ---------------- main: S[i,c] = sum_k dwconv11(gelu(P_i+Q_k+b)) * W_k, conv via MFMA ----------------
// 32x64 output tile (half footprint -> higher residency). Double-buffered GT; ONE barrier
// per iteration; gelu for k+1 interleaved into the conv of k at tx-chunk granularity.
// Wave w: rows rh=w&1 (16 rows), tx pair txp=w>>1 (tx = 2*txp, 2*txp+1).
#define GPITCH 88
#define GROWS2 42
#define GDW2   (GROWS2 * GPITCH / 2)   // 1848 dwords per buffer
#define NU3    8

__global__ __launch_bounds__(256, 3) void k_main(
    const u32* __restrict__ Ph, const u32* __restrict__ Qh,
    const u32* __restrict__ Wh, const float* __restrict__ conf,
    const u32* __restrict__ mm,
    const float* __restrict__ a1b, const float* __restrict__ dww,
    const float* __restrict__ dwb, u32* __restrict__ Sh)
{
    const int tile = blockIdx.x;              // 0..7: (y-tile of 32) x (x-tile of 64)
    const int c    = blockIdx.y;              // 0..63
    const int i    = blockIdx.z;              // 0..5
    const int y0 = (tile >> 1) * 32;
    const int x0 = (tile & 1) * 64;
    const int t    = threadIdx.x;
    const int lane = t & 63;
    const int w    = t >> 6;
    const int rh   = w & 1;                   // row half (16 rows each)
    const int txp  = w >> 1;                  // tx pair: {2*txp, 2*txp+1}
    const int lm   = lane & 15;
    const int kg   = lane >> 4;
    const int kg8  = kg * 8;

    __shared__ __align__(16) u32 GT32[2 * GDW2];

    const float bdw = dwb[c];
    const float ba1 = a1b[c];

    // A fragments: Toeplitz band A[m][k] = w[dy][k-m-3]
    const float* wc = dww + c * 121;
    f16x8 afrag[11];
    #pragma unroll
    for (int dy = 0; dy < 11; ++dy) {
        f16x8 a;
        #pragma unroll
        for (int j = 0; j < 8; ++j) {
            int d = kg8 + j - lm - 3;
            int dcl = min(max(d, 0), 10);
            float wv = wc[dy * 11 + dcl];
            a[j] = (__fp16)((d == dcl) ? wv : 0.f);
        }
        afrag[dy] = a;
    }

    f16x2v bias2; bias2.x = (__fp16)ba1; bias2.y = (__fp16)ba1;

    // preload P pairs (+bias) and pair offsets
    int offs[NU3];
    u32 preg[NU3];
    const u32* Pc = Ph + (size_t)(i * CC + c) * HWP;
    #pragma unroll
    for (int u = 0; u < NU3; ++u) {
        int d = t + u * 256;
        int row = d / (GPITCH / 2);
        int cp  = d - row * (GPITCH / 2);
        int gy = y0 + row - 5;
        int gx = x0 + 2 * cp - 8;
        bool inb = (d < GDW2) && (gy >= 0) && (gy < HH) && (gx >= 0) && (gx < WW);
        offs[u] = inb ? (gy * (WW / 2) + (gx >> 1)) : -1;
        u32 p = 0u;
        if (inb) {
            f16x2v ph = __builtin_bit_cast(f16x2v, Pc[offs[u]]) + bias2;
            p = __builtin_bit_cast(u32, ph);
        }
        preg[u] = p;
    }

    const int oy  = y0 + rh * 16 + lm;
    const int obx = x0 + kg * 4;
    const int obase = oy * WW + obx;
    const int rowb = (rh * 16 + lm) * GPITCH + kg8;

    f32x4 sacc[2];
    sacc[0] = (f32x4){0.f, 0.f, 0.f, 0.f};
    sacc[1] = (f32x4){0.f, 0.f, 0.f, 0.f};

    // ---- prologue: qreg = Q[0]; gelu -> GT[0]; qreg = Q[1]; barrier
    u32 qreg[NU3];
    {
        const u32* Qc = Qh + (size_t)(0 * CC + c) * HWP;
        #pragma unroll
        for (int u = 0; u < NU3; ++u)
            qreg[u] = (offs[u] >= 0) ? Qc[offs[u]] : 0u;
    }
    #pragma unroll
    for (int u = 0; u < NU3; ++u) {
        int d = t + u * 256;
        if (u < NU3 - 1 || d < GDW2) {
            f16x2v s = __builtin_bit_cast(f16x2v, preg[u]) +
                       __builtin_bit_cast(f16x2v, qreg[u]);
            GT32[d] = gelu_pk(__builtin_bit_cast(u32, s));
        }
    }
    {
        const u32* Qc = Qh + (size_t)(1 * CC + c) * HWP;
        #pragma unroll
        for (int u = 0; u < NU3; ++u)
            qreg[u] = (offs[u] >= 0) ? Qc[offs[u]] : 0u;
    }
    __syncthreads();

    #pragma unroll 1
    for (int k = 0; k < NAG; ++k) {
        const __fp16* GTh = (const __fp16*)(GT32 + (k & 1) * GDW2);
        u32* GW = GT32 + ((k + 1) & 1) * GDW2;
        const bool dog = (k + 1 < NAG);
        const bool doq = (k + 2 < NAG);
        const u32* Qc2 = Qh + (size_t)((doq ? k + 2 : 0) * CC + c) * HWP;
        const u32* Wc  = Wh + (size_t)(k * CC + c) * HWP + (obase >> 1);

        // ---- 2 conv chunks (LDS+MFMA), each followed by a gelu slice (VALU+ds_write)
        #pragma unroll
        for (int j = 0; j < 2; ++j) {
            const int tx = 2 * txp + j;
            uint2 wvt = *(const uint2*)(Wc + 8 * tx);
            f32x4 acc = (f32x4){0.f, 0.f, 0.f, 0.f};
            __builtin_amdgcn_s_setprio(1);
            #pragma unroll
            for (int dy = 0; dy < 11; ++dy) {
                f16x8 b = *(const f16x8*)(GTh + rowb + dy * GPITCH + 16 * tx);
                acc = __builtin_amdgcn_mfma_f32_16x16x32_f16(afrag[dy], b, acc, 0, 0, 0);
            }
            __builtin_amdgcn_s_setprio(0);
            f16x2v w0 = __builtin_bit_cast(f16x2v, wvt.x);
            f16x2v w1 = __builtin_bit_cast(f16x2v, wvt.y);
            f32x4 wf = (f32x4){(float)w0.x, (float)w0.y, (float)w1.x, (float)w1.y};
            sacc[j] += (acc + bdw) * wf;

            if (dog) {
                const int u0 = j * 4;
                const int u1 = j * 4 + 4;
                #pragma unroll
                for (int u = u0; u < u1; ++u) {
                    int d = t + u * 256;
                    if (u < NU3 - 1 || d < GDW2) {
                        f16x2v s = __builtin_bit_cast(f16x2v, preg[u]) +
                                   __builtin_bit_cast(f16x2v, qreg[u]);
                        GW[d] = gelu_pk(__builtin_bit_cast(u32, s));
                        if (doq) qreg[u] = (offs[u] >= 0) ? Qc2[offs[u]] : 0u;
                    }
                }
            }
        }

        if (dog) __syncthreads();
    }

    // ---- epilogue: multiply by (1 - conf_norm_i), store packed f16
    const float mn = __uint_as_float(mm[i]);
    const float mx = __uint_as_float(mm[i + NAG]);
    const float inv = 1.f / (mx - mn);
    const float* cfi = conf + i * HWT + obase;
    u32* Sc = Sh + (size_t)(i * CC + c) * HWP + (obase >> 1);
    #pragma unroll
    for (int j = 0; j < 2; ++j) {
        const int tx = 2 * txp + j;
        f32x4 cv = *(const f32x4*)(cfi + 16 * tx);
        f32x4 r = sacc[j] * (1.f - (cv - mn) * inv);
        f16x2v h0 = __builtin_amdgcn_cvt_pkrtz(r[0], r[1]);
        f16x2v h1 = __builtin_amdgcn_cvt_pkrtz(r[2], r[3]);
        *(uint2*)(Sc + 8 * tx) = make_uint2(__builtin_bit_cast(u32, h0),
                                            __builtin_bit_cast(u32, h1));
    }
}

// ---------------- MFMA epilogue: out = raw + projW * Sh + 6*pb ----------------
__global__ __launch_bounds__(256) void k_out(
    const u32* __restrict__ Sh, const float* __restrict__ raw,
    const __fp16* __restrict__ wfrag, const float* __restrict__ pb,
    float* __restrict__ out)
{
    const int n   = blockIdx.y;
    const int px0 = blockIdx.x * 128;
    const int t = threadIdx.x, lane = t & 63, wv = t >> 6;
    const int lm = lane & 15, kg = lane >> 4;
    const int pxw = px0 + wv * 32;
    const int pxl = pxw + lm;
    const int pxs = pxw + kg * 4;

    const u32* Sn = Sh + (size_t)n * CC * HWP;
    const u32 sh = (pxl & 1) * 16;

    f16x8 afr[2][2];
    #pragma unroll
    for (int mt = 0; mt < 2; ++mt) {
        #pragma unroll
        for (int kf = 0; kf < 2; ++kf) {
            const u32* base = Sn + (size_t)(kf * 32 + kg * 8) * HWP + ((pxl + mt * 16) >> 1);
            f16x8 a;
            #pragma unroll
            for (int j = 0; j < 8; ++j) {
                unsigned short v = (unsigned short)(base[(size_t)j * HWP] >> sh);
                a[j] = __builtin_bit_cast(__fp16, v);
            }
            afr[mt][kf] = a;
        }
    }

    #pragma unroll
    for (int ot = 0; ot < 4; ++ot) {
        f16x8 b0 = *(const f16x8*)(wfrag + WFRAG_PJ_OFF +
                                   ((size_t)(ot * 2 + 0) * 64 + lane) * 8);
        f16x8 b1 = *(const f16x8*)(wfrag + WFRAG_PJ_OFF +
                                   ((size_t)(ot * 2 + 1) * 64 + lane) * 8);
        const int o = ot * 16 + lm;
        const float bias = (float)NAG * pb[o];
        #pragma unroll
        for (int mt = 0; mt < 2; ++mt) {
            f32x4 acc = (f32x4){0.f, 0.f, 0.f, 0.f};
            acc = __builtin_amdgcn_mfma_f32_16x16x32_f16(afr[mt][0], b0, acc, 0, 0, 0);
            acc = __builtin_amdgcn_mfma_f32_16x16x32_f16(afr[mt][1], b1, acc, 0, 0, 0);
            const int pxb = pxs + mt * 16;
            f32x4 r = *(const f32x4*)(raw + (size_t)(n * CC + o) * HWT + pxb);
            f32x4 ov = r + acc + bias;
            *(f32x4*)(out + (size_t)(n * CC + o) * HWT + pxb) = ov;
        }
    }
}

extern "C" void kernel_launch(void* const* d_in, const int* in_sizes, int n_in,
                              void* d_out, int out_size, void* d_ws, size_t ws_size,
                              hipStream_t stream)
{
    (void)in_sizes; (void)n_in; (void)out_size; (void)ws_size;

    const float* raw   = (const float*)d_in[0];
    const float* pw_w1 = (const float*)d_in[1];
    const float* pw_b1 = (const float*)d_in[2];
    const float* bng   = (const float*)d_in[3];
    const float* bnb   = (const float*)d_in[4];
    const float* bnm   = (const float*)d_in[5];
    const float* bnv   = (const float*)d_in[6];
    const float* pw_w2 = (const float*)d_in[7];
    const float* pw_b2 = (const float*)d_in[8];
    const float* a1w   = (const float*)d_in[9];
    const float* a1b   = (const float*)d_in[10];
    const float* dww   = (const float*)d_in[11];
    const float* dwb   = (const float*)d_in[12];
    const float* vw    = (const float*)d_in[13];
    const float* vb    = (const float*)d_in[14];
    const float* pjw   = (const float*)d_in[15];
    const float* pjb   = (const float*)d_in[16];

    float* ws   = (float*)d_ws;
    float* conf = ws;                                    // 6*16384 f32
    u32*   mm   = (u32*)(ws + NAG * HWT);                // 16 u32
    u32*   Ph   = (u32*)(ws + NAG * HWT + 16);           // 6*64*8192 u32
    u32*   Qh   = Ph + (size_t)NAG * CC * HWP;           // 6*64*8192 u32
    u32*   Wh   = Qh + (size_t)NAG * CC * HWP;           // 6*64*8192 u32
    u32*   Sh   = Wh + (size_t)NAG * CC * HWP;           // 6*64*8192 u32
    __fp16* wfrag = (__fp16*)(Sh + (size_t)NAG * CC * HWP); // 16384 halves (32 KB)
    float* out  = (float*)d_out;

    k_setup<<<dim3(8), dim3(256), 0, stream>>>(a1w, vw, pjw, wfrag, mm);
    k_conf<<<dim3(HWT / 1024, NAG), dim3(256), 0, stream>>>(raw, pw_w1, pw_b1, bng, bnb,
                                                            bnm, bnv, pw_w2, pw_b2, conf, mm);
    k_pqv<<<dim3(HWT / 128, NAG), dim3(256), 0, stream>>>(raw, wfrag, vb, conf, mm,
                                                          Ph, Qh, Wh);
    k_main<<<dim3(8, CC, NAG), dim3(256), 0, stream>>>(Ph, Qh, Wh, conf, mm, a1b, dww, dwb, Sh);
    k_out<<<dim3(HWT / 128, NAG), dim3(256), 0, stream>>>(Sh, raw, wfrag, pjb, out);
}

// Round 17
// 99.480 us; speedup vs baseline: 1.1451x; 1.1451x over previous
//
#include <hip/hip_runtime.h>
#include <hip/hip_fp16.h>
#include <math.h>

#define NAG 6
#define CC  64
#define HH  128
#define WW  128
#define HWT 16384
#define HWP 8192             // packed f16 pairs per (agent,channel) plane
#define BN_EPS 1e-5f
#define WFRAG_PJ_OFF (24 * 64 * 8)   // halves: P/Q/W slots first, then proj slots

typedef unsigned int u32;
typedef __fp16 f16x2v __attribute__((ext_vector_type(2)));
typedef __fp16 f16x8  __attribute__((ext_vector_type(8)));
typedef float  f32x4  __attribute__((ext_vector_type(4)));

// packed-f16 tanh-form gelu, exp2-folded
__device__ __forceinline__ u32 gelu_pk(u32 xu) {
    __half2 x = __builtin_bit_cast(__half2, xu);
    __half2 s = __hmul2(x, x);
    __half2 m = __hfma2(s, __float2half2_rn(-0.10294535f),
                        __float2half2_rn(-2.30226045f));
    __half2 e = h2exp2(__hmul2(x, m));
    __half2 r = h2rcp(__hadd2(e, __float2half2_rn(1.0f)));
    return __builtin_bit_cast(u32, __hmul2(x, r));
}

// ---------------- setup: min/max slots + weight prepack (one launch) ----------------
__global__ __launch_bounds__(256) void k_setup(
    const float* __restrict__ a1w, const float* __restrict__ vw,
    const float* __restrict__ pjw, __fp16* __restrict__ wfrag,
    u32* __restrict__ mm)
{
    int t = blockIdx.x * 256 + threadIdx.x;
    if (t < NAG) mm[t] = 0x7F800000u;        // +inf (min slots)
    else if (t < 2 * NAG) mm[t] = 0u;        // 0 (max; conf >= 0)
    if (t >= 32 * 64) return;
    int lane = t & 63;
    int slot = t >> 6;
    bool pj = slot >= 24;
    int s = pj ? slot - 24 : slot;
    int ot = s >> 1, kf = s & 1;
    int o  = (pj ? ot : (ot & 3)) * 16 + (lane & 15);
    int ch = kf * 32 + (lane >> 4) * 8;
    const float* src;
    if (pj)          src = pjw + o * CC + ch;
    else if (ot < 4) src = a1w + o * 2 * CC + ch;            // A1 (P)
    else if (ot < 8) src = a1w + o * 2 * CC + CC + ch;       // A2 (Q)
    else             src = vw  + o * CC + ch;                // V  (W)
    __fp16* dst = wfrag + ((size_t)slot * 64 + lane) * 8;
    #pragma unroll
    for (int j = 0; j < 8; ++j) dst[j] = (__fp16)src[j];
}

// ---------------- confidence maps (pre-normalization) + per-agent min/max ----------------
// vectorized: 4 px per thread via float4 (16 B/lane)
__global__ __launch_bounds__(256) void k_conf(
    const float* __restrict__ raw,
    const float* __restrict__ w1, const float* __restrict__ b1,
    const float* __restrict__ gamma, const float* __restrict__ beta,
    const float* __restrict__ mean, const float* __restrict__ var,
    const float* __restrict__ w2, const float* __restrict__ b2,
    float* __restrict__ conf, u32* __restrict__ mm)
{
    const int n = blockIdx.y;
    const int p = (blockIdx.x * 256 + threadIdx.x) * 4;
    const float* x = raw + (size_t)(n * CC) * HWT + p;

    f32x4 a[4];
    #pragma unroll
    for (int o = 0; o < 4; ++o) a[o] = (f32x4){0.f, 0.f, 0.f, 0.f};

    #pragma unroll 8
    for (int c = 0; c < CC; ++c) {
        f32x4 v = *(const f32x4*)(x + (size_t)c * HWT);
        #pragma unroll
        for (int o = 0; o < 4; ++o)
            a[o] += w1[o * CC + c] * v;
    }
    f32x4 h2 = (f32x4){b2[0], b2[0], b2[0], b2[0]};
    #pragma unroll
    for (int o = 0; o < 4; ++o) {
        float sc = gamma[o] * rsqrtf(var[o] + BN_EPS);
        float off = (b1[o] - mean[o]) * sc + beta[o];
        f32x4 hb = a[o] * sc + off;
        #pragma unroll
        for (int q = 0; q < 4; ++q) hb[q] = fmaxf(hb[q], 0.f);
        h2 += w2[o] * hb;
    }
    #pragma unroll
    for (int q = 0; q < 4; ++q) h2[q] = fmaxf(h2[q], 0.f);
    *(f32x4*)(conf + n * HWT + p) = h2;

    float mn = fminf(fminf(h2[0], h2[1]), fminf(h2[2], h2[3]));
    float mx = fmaxf(fmaxf(h2[0], h2[1]), fmaxf(h2[2], h2[3]));
    #pragma unroll
    for (int off = 32; off > 0; off >>= 1) {
        mn = fminf(mn, __shfl_xor(mn, off, 64));
        mx = fmaxf(mx, __shfl_xor(mx, off, 64));
    }
    __shared__ float smn[4], smx[4];
    int wid = threadIdx.x >> 6, lane = threadIdx.x & 63;
    if (lane == 0) { smn[wid] = mn; smx[wid] = mx; }
    __syncthreads();
    if (threadIdx.x == 0) {
        mn = fminf(fminf(smn[0], smn[1]), fminf(smn[2], smn[3]));
        mx = fmaxf(fmaxf(smx[0], smx[1]), fmaxf(smx[2], smx[3]));
        atomicMin(&mm[n], __float_as_uint(mn));
        atomicMax(&mm[n + NAG], __float_as_uint(mx));
    }
}

// ---------------- MFMA GEMM: P/Q (f16) + W (f16, conf-scaled) in one pass over raw ----------------
__global__ __launch_bounds__(256) void k_pqv(
    const float* __restrict__ raw, const __fp16* __restrict__ wfrag,
    const float* __restrict__ vb, const float* __restrict__ conf,
    const u32* __restrict__ mm,
    u32* __restrict__ Ph, u32* __restrict__ Qh, u32* __restrict__ Wh)
{
    const int n   = blockIdx.y;
    const int px0 = blockIdx.x * 128;
    const int t = threadIdx.x, lane = t & 63, wv = t >> 6;
    const int lm = lane & 15, kg = lane >> 4;
    const int pxw = px0 + wv * 32;
    const int pxl = pxw + lm;           // A-frag px (+ mt*16)
    const int pxs = pxw + kg * 4;       // store px base (+ mt*16)

    const float* rawn = raw + (size_t)n * CC * HWT;

    f16x8 afr[2][2];
    #pragma unroll
    for (int mt = 0; mt < 2; ++mt) {
        #pragma unroll
        for (int kf = 0; kf < 2; ++kf) {
            const float* base = rawn + (size_t)(kf * 32 + kg * 8) * HWT + pxl + mt * 16;
            f16x8 a;
            #pragma unroll
            for (int p = 0; p < 4; ++p) {
                f16x2v h = __builtin_amdgcn_cvt_pkrtz(base[(2 * p) * HWT],
                                                      base[(2 * p + 1) * HWT]);
                a[2 * p] = h.x; a[2 * p + 1] = h.y;
            }
            afr[mt][kf] = a;
        }
    }

    const float mn = __uint_as_float(mm[n]);
    const float mx = __uint_as_float(mm[n + NAG]);
    const float inv = 1.f / (mx - mn);
    f32x4 cn[2];
    #pragma unroll
    for (int mt = 0; mt < 2; ++mt) {
        f32x4 cv = *(const f32x4*)(conf + n * HWT + pxs + mt * 16);
        cn[mt] = (cv - mn) * inv;
    }

    #pragma unroll
    for (int ot = 0; ot < 12; ++ot) {
        f16x8 b0 = *(const f16x8*)(wfrag + ((size_t)(ot * 2 + 0) * 64 + lane) * 8);
        f16x8 b1 = *(const f16x8*)(wfrag + ((size_t)(ot * 2 + 1) * 64 + lane) * 8);
        const int o = (ot & 3) * 16 + lm;
        #pragma unroll
        for (int mt = 0; mt < 2; ++mt) {
            f32x4 acc = (f32x4){0.f, 0.f, 0.f, 0.f};
            acc = __builtin_amdgcn_mfma_f32_16x16x32_f16(afr[mt][0], b0, acc, 0, 0, 0);
            acc = __builtin_amdgcn_mfma_f32_16x16x32_f16(afr[mt][1], b1, acc, 0, 0, 0);
            const int pxb = pxs + mt * 16;
            f32x4 r;
            u32* plane;
            if (ot < 8) {
                r = acc;
                plane = (ot < 4 ? Ph : Qh) + (size_t)(n * CC + o) * HWP + (pxb >> 1);
            } else {
                r = (acc + vb[o]) * cn[mt];
                plane = Wh + (size_t)(n * CC + o) * HWP + (pxb >> 1);
            }
            f16x2v h0 = __builtin_amdgcn_cvt_pkrtz(r[0], r[1]);
            f16x2v h1 = __builtin_amdgcn_cvt_pkrtz(r[2], r[3]);
            *(uint2*)plane = make_uint2(__builtin_bit_cast(u32, h0),
                                        __builtin_bit_cast(u32, h1));
        }
    }
}

// ---------------- main: S[i,c] = sum_k dwconv11(gelu(P_i+Q_k+b)) * W_k, conv via MFMA ----------------
// Double-buffered GT; ONE barrier per iteration. gelu for k+1 is interleaved into the
// conv of k at tx granularity so VALU work dual-issues against LDS/MFMA within a wave.
#define GPITCH 88
#define GROWS  74
#define GDW    (GROWS * GPITCH / 2)   // 3256 dwords per buffer
#define NU2    13

__global__ __launch_bounds__(256, 3) void k_main(
    const u32* __restrict__ Ph, const u32* __restrict__ Qh,
    const u32* __restrict__ Wh, const float* __restrict__ conf,
    const u32* __restrict__ mm,
    const float* __restrict__ a1b, const float* __restrict__ dww,
    const float* __restrict__ dwb, u32* __restrict__ Sh)
{
    const int tile = blockIdx.x;              // 0..3 image quadrant
    const int c    = blockIdx.y;              // 0..63
    const int i    = blockIdx.z;              // 0..5
    const int y0 = (tile >> 1) * 64;
    const int x0 = (tile & 1) * 64;
    const int t    = threadIdx.x;
    const int lane = t & 63;
    const int ty   = t >> 6;
    const int lm   = lane & 15;
    const int kg   = lane >> 4;
    const int kg8  = kg * 8;

    __shared__ __align__(16) u32 GT32[2 * GDW];

    const float bdw = dwb[c];
    const float ba1 = a1b[c];

    // A fragments: Toeplitz band A[m][k] = w[dy][k-m-3]
    const float* wc = dww + c * 121;
    f16x8 afrag[11];
    #pragma unroll
    for (int dy = 0; dy < 11; ++dy) {
        f16x8 a;
        #pragma unroll
        for (int j = 0; j < 8; ++j) {
            int d = kg8 + j - lm - 3;
            int dcl = min(max(d, 0), 10);
            float wv = wc[dy * 11 + dcl];
            a[j] = (__fp16)((d == dcl) ? wv : 0.f);
        }
        afrag[dy] = a;
    }

    f16x2v bias2; bias2.x = (__fp16)ba1; bias2.y = (__fp16)ba1;

    // preload P pairs (+bias) and pair offsets
    int offs[NU2];
    u32 preg[NU2];
    const u32* Pc = Ph + (size_t)(i * CC + c) * HWP;
    #pragma unroll
    for (int u = 0; u < NU2; ++u) {
        int d = t + u * 256;
        int row = d / (GPITCH / 2);
        int cp  = d - row * (GPITCH / 2);
        int gy = y0 + row - 5;
        int gx = x0 + 2 * cp - 8;
        bool inb = (d < GDW) && (gy >= 0) && (gy < HH) && (gx >= 0) && (gx < WW);
        offs[u] = inb ? (gy * (WW / 2) + (gx >> 1)) : -1;
        u32 p = 0u;
        if (inb) {
            f16x2v ph = __builtin_bit_cast(f16x2v, Pc[offs[u]]) + bias2;
            p = __builtin_bit_cast(u32, ph);
        }
        preg[u] = p;
    }

    const int oy  = y0 + ty * 16 + lm;
    const int obx = x0 + kg * 4;
    const int obase = oy * WW + obx;
    const int rowb = (ty * 16 + lm) * GPITCH + kg8;

    f32x4 sacc[4];
    #pragma unroll
    for (int tx = 0; tx < 4; ++tx) sacc[tx] = (f32x4){0.f, 0.f, 0.f, 0.f};

    // ---- prologue: qreg = Q[0]; gelu -> GT[0]; qreg = Q[1]; barrier
    u32 qreg[NU2];
    {
        const u32* Qc = Qh + (size_t)(0 * CC + c) * HWP;
        #pragma unroll
        for (int u = 0; u < NU2; ++u)
            qreg[u] = (offs[u] >= 0) ? Qc[offs[u]] : 0u;
    }
    #pragma unroll
    for (int u = 0; u < NU2; ++u) {
        int d = t + u * 256;
        if (u < NU2 - 1 || d < GDW) {
            f16x2v s = __builtin_bit_cast(f16x2v, preg[u]) +
                       __builtin_bit_cast(f16x2v, qreg[u]);
            GT32[d] = gelu_pk(__builtin_bit_cast(u32, s));
        }
    }
    {
        const u32* Qc = Qh + (size_t)(1 * CC + c) * HWP;
        #pragma unroll
        for (int u = 0; u < NU2; ++u)
            qreg[u] = (offs[u] >= 0) ? Qc[offs[u]] : 0u;
    }
    __syncthreads();

    #pragma unroll 1
    for (int k = 0; k < NAG; ++k) {
        const __fp16* GTh = (const __fp16*)(GT32 + (k & 1) * GDW);
        u32* GW = GT32 + ((k + 1) & 1) * GDW;
        const bool dog = (k + 1 < NAG);
        const bool doq = (k + 2 < NAG);
        const u32* Qc2 = Qh + (size_t)((doq ? k + 2 : 0) * CC + c) * HWP;
        const u32* Wc  = Wh + (size_t)(k * CC + c) * HWP + (obase >> 1);

        // ---- 4 conv chunks (LDS+MFMA), each followed by a gelu slice (VALU+ds_write)
        #pragma unroll
        for (int tx = 0; tx < 4; ++tx) {
            uint2 wvt = *(const uint2*)(Wc + 8 * tx);
            f32x4 acc = (f32x4){0.f, 0.f, 0.f, 0.f};
            __builtin_amdgcn_s_setprio(1);
            #pragma unroll
            for (int dy = 0; dy < 11; ++dy) {
                f16x8 b = *(const f16x8*)(GTh + rowb + dy * GPITCH + 16 * tx);
                acc = __builtin_amdgcn_mfma_f32_16x16x32_f16(afrag[dy], b, acc, 0, 0, 0);
            }
            __builtin_amdgcn_s_setprio(0);
            f16x2v w0 = __builtin_bit_cast(f16x2v, wvt.x);
            f16x2v w1 = __builtin_bit_cast(f16x2v, wvt.y);
            f32x4 wf = (f32x4){(float)w0.x, (float)w0.y, (float)w1.x, (float)w1.y};
            sacc[tx] += (acc + bdw) * wf;

            if (dog) {
                const int u0 = (tx == 3) ? 9 : tx * 3;
                const int u1 = (tx == 3) ? NU2 : tx * 3 + 3;
                #pragma unroll
                for (int u = u0; u < u1; ++u) {
                    int d = t + u * 256;
                    if (u < NU2 - 1 || d < GDW) {
                        f16x2v s = __builtin_bit_cast(f16x2v, preg[u]) +
                                   __builtin_bit_cast(f16x2v, qreg[u]);
                        GW[d] = gelu_pk(__builtin_bit_cast(u32, s));
                        if (doq) qreg[u] = (offs[u] >= 0) ? Qc2[offs[u]] : 0u;
                    }
                }
            }
        }

        if (dog) __syncthreads();
    }

    // ---- epilogue: multiply by (1 - conf_norm_i), store packed f16
    const float mn = __uint_as_float(mm[i]);
    const float mx = __uint_as_float(mm[i + NAG]);
    const float inv = 1.f / (mx - mn);
    const float* cfi = conf + i * HWT + obase;
    u32* Sc = Sh + (size_t)(i * CC + c) * HWP + (obase >> 1);
    #pragma unroll
    for (int tx = 0; tx < 4; ++tx) {
        f32x4 cv = *(const f32x4*)(cfi + 16 * tx);
        f32x4 r = sacc[tx] * (1.f - (cv - mn) * inv);
        f16x2v h0 = __builtin_amdgcn_cvt_pkrtz(r[0], r[1]);
        f16x2v h1 = __builtin_amdgcn_cvt_pkrtz(r[2], r[3]);
        *(uint2*)(Sc + 8 * tx) = make_uint2(__builtin_bit_cast(u32, h0),
                                            __builtin_bit_cast(u32, h1));
    }
}

// ---------------- MFMA epilogue: out = raw + projW * Sh + 6*pb ----------------
__global__ __launch_bounds__(256) void k_out(
    const u32* __restrict__ Sh, const float* __restrict__ raw,
    const __fp16* __restrict__ wfrag, const float* __restrict__ pb,
    float* __restrict__ out)
{
    const int n   = blockIdx.y;
    const int px0 = blockIdx.x * 128;
    const int t = threadIdx.x, lane = t & 63, wv = t >> 6;
    const int lm = lane & 15, kg = lane >> 4;
    const int pxw = px0 + wv * 32;
    const int pxl = pxw + lm;
    const int pxs = pxw + kg * 4;

    const u32* Sn = Sh + (size_t)n * CC * HWP;
    const u32 sh = (pxl & 1) * 16;

    f16x8 afr[2][2];
    #pragma unroll
    for (int mt = 0; mt < 2; ++mt) {
        #pragma unroll
        for (int kf = 0; kf < 2; ++kf) {
            const u32* base = Sn + (size_t)(kf * 32 + kg * 8) * HWP + ((pxl + mt * 16) >> 1);
            f16x8 a;
            #pragma unroll
            for (int j = 0; j < 8; ++j) {
                unsigned short v = (unsigned short)(base[(size_t)j * HWP] >> sh);
                a[j] = __builtin_bit_cast(__fp16, v);
            }
            afr[mt][kf] = a;
        }
    }

    #pragma unroll
    for (int ot = 0; ot < 4; ++ot) {
        f16x8 b0 = *(const f16x8*)(wfrag + WFRAG_PJ_OFF +
                                   ((size_t)(ot * 2 + 0) * 64 + lane) * 8);
        f16x8 b1 = *(const f16x8*)(wfrag + WFRAG_PJ_OFF +
                                   ((size_t)(ot * 2 + 1) * 64 + lane) * 8);
        const int o = ot * 16 + lm;
        const float bias = (float)NAG * pb[o];
        #pragma unroll
        for (int mt = 0; mt < 2; ++mt) {
            f32x4 acc = (f32x4){0.f, 0.f, 0.f, 0.f};
            acc = __builtin_amdgcn_mfma_f32_16x16x32_f16(afr[mt][0], b0, acc, 0, 0, 0);
            acc = __builtin_amdgcn_mfma_f32_16x16x32_f16(afr[mt][1], b1, acc, 0, 0, 0);
            const int pxb = pxs + mt * 16;
            f32x4 r = *(const f32x4*)(raw + (size_t)(n * CC + o) * HWT + pxb);
            f32x4 ov = r + acc + bias;
            *(f32x4*)(out + (size_t)(n * CC + o) * HWT + pxb) = ov;
        }
    }
}

extern "C" void kernel_launch(void* const* d_in, const int* in_sizes, int n_in,
                              void* d_out, int out_size, void* d_ws, size_t ws_size,
                              hipStream_t stream)
{
    (void)in_sizes; (void)n_in; (void)out_size; (void)ws_size;

    const float* raw   = (const float*)d_in[0];
    const float* pw_w1 = (const float*)d_in[1];
    const float* pw_b1 = (const float*)d_in[2];
    const float* bng   = (const float*)d_in[3];
    const float* bnb   = (const float*)d_in[4];
    const float* bnm   = (const float*)d_in[5];
    const float* bnv   = (const float*)d_in[6];
    const float* pw_w2 = (const float*)d_in[7];
    const float* pw_b2 = (const float*)d_in[8];
    const float* a1w   = (const float*)d_in[9];
    const float* a1b   = (const float*)d_in[10];
    const float* dww   = (const float*)d_in[11];
    const float* dwb   = (const float*)d_in[12];
    const float* vw    = (const float*)d_in[13];
    const float* vb    = (const float*)d_in[14];
    const float* pjw   = (const float*)d_in[15];
    const float* pjb   = (const float*)d_in[16];

    float* ws   = (float*)d_ws;
    float* conf = ws;                                    // 6*16384 f32
    u32*   mm   = (u32*)(ws + NAG * HWT);                // 16 u32
    u32*   Ph   = (u32*)(ws + NAG * HWT + 16);           // 6*64*8192 u32
    u32*   Qh   = Ph + (size_t)NAG * CC * HWP;           // 6*64*8192 u32
    u32*   Wh   = Qh + (size_t)NAG * CC * HWP;           // 6*64*8192 u32
    u32*   Sh   = Wh + (size_t)NAG * CC * HWP;           // 6*64*8192 u32
    __fp16* wfrag = (__fp16*)(Sh + (size_t)NAG * CC * HWP); // 16384 halves (32 KB)
    float* out  = (float*)d_out;

    k_setup<<<dim3(8), dim3(256), 0, stream>>>(a1w, vw, pjw, wfrag, mm);
    k_conf<<<dim3(HWT / 1024, NAG), dim3(256), 0, stream>>>(raw, pw_w1, pw_b1, bng, bnb,
                                                            bnm, bnv, pw_w2, pw_b2, conf, mm);
    k_pqv<<<dim3(HWT / 128, NAG), dim3(256), 0, stream>>>(raw, wfrag, vb, conf, mm,
                                                          Ph, Qh, Wh);
    k_main<<<dim3(4, CC, NAG), dim3(256), 0, stream>>>(Ph, Qh, Wh, conf, mm, a1b, dww, dwb, Sh);
    k_out<<<dim3(HWT / 128, NAG), dim3(256), 0, stream>>>(Sh, raw, wfrag, pjb, out);
}